// Round 7
// baseline (183.837 us; speedup 1.0000x reference)
//
#include <hip/hip_runtime.h>
#include <stdint.h>

typedef float  floatx4 __attribute__((ext_vector_type(4)));
typedef short  short8  __attribute__((ext_vector_type(8)));
typedef float  f4v     __attribute__((ext_vector_type(4)));
typedef unsigned int uint32;

#define GS_EPS 1e-10f

__device__ __forceinline__ unsigned short f2bf(float x) {
  uint32 u = __float_as_uint(x);
  u += 0x7FFFu + ((u >> 16) & 1u);
  return (unsigned short)(u >> 16);
}
__device__ __forceinline__ float bf2f(short v) {
  return __uint_as_float(((uint32)(unsigned short)v) << 16);
}
// sign-extend byte j (0..3) of w, to float
__device__ __forceinline__ float i8tof(uint32 w, int j) {
  int b = (int)(w << (24 - 8 * j)) >> 24;
  return (float)b;
}

// ---- prep: W1 fp32 [256][64] -> W1cat bf16 blocked [chunk=k/8][n=0..128)][k%8]
// W1cat[k][n] = n<64 ? W1[k][n] : W1[128+k][n-64]; also zero the gmax slots.
__global__ void conv_w1cat_kernel(const float* __restrict__ W1,
                                  unsigned short* __restrict__ w1g,
                                  uint32* __restrict__ gmax) {
  if (blockIdx.x == 0 && threadIdx.x < 2) gmax[threadIdx.x] = 0u;
  int i = blockIdx.x * 256 + threadIdx.x;  // 0..2047 = chunk*128 + n
  int chunk = i >> 7;
  int n = i & 127;
  const float* src = (n < 64) ? (W1 + n) : (W1 + 128 * 64 + (n - 64));
  uint32 d[4];
#pragma unroll
  for (int j = 0; j < 4; ++j) {
    int k0 = chunk * 8 + 2 * j;
    unsigned short lo = f2bf(src[(size_t)k0 * 64]);
    unsigned short hi = f2bf(src[(size_t)(k0 + 1) * 64]);
    d[j] = (uint32)lo | ((uint32)hi << 16);
  }
#pragma unroll
  for (int j = 0; j < 4; ++j) *(uint32*)&w1g[(size_t)i * 8 + 2 * j] = d[j];
}

// ---- precompute P[node][0:64]=e@W1_top+b1, P[node][64:128]=e@W1_bot (bf16),
// plus global absmax of each half (atomicMax on positive-float bit pattern). ----
// MFMA mapping (validated R4): D col = node = l16, row = j = t*16 + q*4 + r.
__global__ __launch_bounds__(512, 4) void pcompute_kernel(
    const float* __restrict__ E, const unsigned short* __restrict__ w1g,
    const float* __restrict__ b1, unsigned short* __restrict__ P,
    uint32* __restrict__ gmax, int num_nodes) {
  __shared__ __align__(16) unsigned short w1blk[16 * 128 * 8];  // 32 KB

  const int tid = threadIdx.x;
  const int wave = tid >> 6;
  const int lane = tid & 63;
  const int q = lane >> 4;
  const int l16 = lane & 15;

#pragma unroll
  for (int it = 0; it < 4; ++it) {
    int idx = it * 512 + tid;
    short8 v = *(const short8*)(w1g + (size_t)idx * 8);
    *(short8*)&w1blk[(size_t)idx * 8] = v;
  }

  const int rowbase = blockIdx.x * 128 + wave * 16;
  int row = rowbase + l16;
  const bool ok = row < num_nodes;
  if (!ok) row = num_nodes - 1;

  short8 bfr[4];
#pragma unroll
  for (int kk = 0; kk < 4; ++kk) {
    const float* p = E + (size_t)row * 128 + kk * 32 + q * 8;
    f4v v0 = *(const f4v*)p;
    f4v v1 = *(const f4v*)(p + 4);
    short8 t;
    t[0] = (short)f2bf(v0[0]); t[1] = (short)f2bf(v0[1]);
    t[2] = (short)f2bf(v0[2]); t[3] = (short)f2bf(v0[3]);
    t[4] = (short)f2bf(v1[0]); t[5] = (short)f2bf(v1[1]);
    t[6] = (short)f2bf(v1[2]); t[7] = (short)f2bf(v1[3]);
    bfr[kk] = t;
  }
  __syncthreads();

  floatx4 acc[8];
#pragma unroll
  for (int t = 0; t < 8; ++t) {
    floatx4 z = {0.f, 0.f, 0.f, 0.f};
    acc[t] = z;
  }
#pragma unroll
  for (int kk = 0; kk < 4; ++kk) {
#pragma unroll
    for (int t = 0; t < 8; ++t) {
      short8 af = *(const short8*)&w1blk[(size_t)((kk * 4 + q) * 128 + t * 16 + l16) * 8];
      acc[t] = __builtin_amdgcn_mfma_f32_16x16x32_bf16(af, bfr[kk], acc[t], 0, 0, 0);
    }
  }

  // fold b1 into top half (j<64 <=> t<4); write bf16 P; track half absmax
  float mtop = 0.f, mbot = 0.f;
#pragma unroll
  for (int t = 0; t < 8; ++t) {
    floatx4 a = acc[t];
    if (t < 4) {
      f4v bv = *(const f4v*)(b1 + t * 16 + q * 4);
      a[0] += bv[0]; a[1] += bv[1]; a[2] += bv[2]; a[3] += bv[3];
    }
    float m = fmaxf(fmaxf(fabsf(a[0]), fabsf(a[1])), fmaxf(fabsf(a[2]), fabsf(a[3])));
    if (t < 4) mtop = fmaxf(mtop, m); else mbot = fmaxf(mbot, m);
    uint32 lo = (uint32)f2bf(a[0]) | ((uint32)f2bf(a[1]) << 16);
    uint32 hi = (uint32)f2bf(a[2]) | ((uint32)f2bf(a[3]) << 16);
    if (ok) {
      uint32* dst = (uint32*)(P + (size_t)(rowbase + l16) * 128 + t * 16 + q * 4);
      dst[0] = lo;
      dst[1] = hi;
    }
  }
  // full-wave max reduce, one atomic per wave per half
#pragma unroll
  for (int s = 1; s < 64; s <<= 1) {
    mtop = fmaxf(mtop, __shfl_xor(mtop, s, 64));
    mbot = fmaxf(mbot, __shfl_xor(mbot, s, 64));
  }
  if (lane == 0) {
    atomicMax(&gmax[0], __float_as_uint(mtop));  // positive floats: uint order ok
    atomicMax(&gmax[1], __float_as_uint(mbot));
  }
}

// ---- quantize bf16 P -> combined int8 table P8[node][128] = {top64, bot64} ----
__global__ __launch_bounds__(256) void quant_kernel(
    const unsigned short* __restrict__ P, const uint32* __restrict__ gmax,
    uint8_t* __restrict__ P8, int total16) {
  int i = blockIdx.x * 256 + threadIdx.x;  // one thread = 16 values
  if (i >= total16) return;
  const float at = __uint_as_float(gmax[0]);
  const float ab = __uint_as_float(gmax[1]);
  const float invt = 127.f / fmaxf(at, 1e-20f);
  const float invb = 127.f / fmaxf(ab, 1e-20f);
  // offset i*16; within a 128-elem row, (i&7)<4 -> top half
  const float inv = ((i & 7) < 4) ? invt : invb;
  const size_t off = (size_t)i * 16;
  short8 v0 = *(const short8*)(P + off);
  short8 v1 = *(const short8*)(P + off + 8);
  uint32 outw[4];
#pragma unroll
  for (int w = 0; w < 4; ++w) {
    uint32 r = 0;
#pragma unroll
    for (int j = 0; j < 4; ++j) {
      short s = (w < 2) ? v0[w * 4 + j] : v1[(w - 2) * 4 + j];
      float x = bf2f(s) * inv;
      x = fminf(fmaxf(x, -127.f), 127.f);
      int vq = (int)__builtin_rintf(x);
      r |= ((uint32)(vq & 255)) << (8 * j);
    }
    outw[w] = r;
  }
  *(uint4*)(P8 + off) = *(uint4*)outw;
}

// ---- edge kernel: 2 random 64B gathers/edge + dequant dot + gumbel-sigmoid ----
// Block 256 = 4 waves; wave = 32 edges = 4 slots of 8 edges; 8 lanes/edge.
__global__ __launch_bounds__(256, 8) void edge_kernel(
    const uint8_t* __restrict__ P8, const uint32* __restrict__ gmax,
    const int* __restrict__ ei,
    const float* __restrict__ u1, const float* __restrict__ u2,
    const float* __restrict__ W2, const float* __restrict__ b2,
    float* __restrict__ out, int num_edges) {
  const int tid = threadIdx.x;
  const int wave = tid >> 6;
  const int lane = tid & 63;
  const int g = lane >> 3;  // edge-within-slot
  const int h = lane & 7;   // lane-within-edge
  const int wbase = blockIdx.x * 128 + wave * 32;

  const float st = __uint_as_float(gmax[0]) * (1.f / 127.f);  // uniform scalar
  const float sb = __uint_as_float(gmax[1]) * (1.f / 127.f);
  f4v w0 = *(const f4v*)(W2 + h * 8);
  f4v w1v = *(const f4v*)(W2 + h * 8 + 4);
  const float bias2 = b2[0];

  int el = wbase + (lane & 31);
  if (el > num_edges - 1) el = num_edges - 1;
  // int64-vs-int32 detection (per-wave uniform): int64 LE => odd words all 0
  unsigned long long oddmask = __ballot(ei[2 * el + 1] != 0);
  const bool idx64 = (oddmask == 0ULL);
  int eR, eC;
  if (idx64) {
    eR = ei[2 * el];
    eC = ei[2 * (num_edges + el)];
  } else {
    eR = ei[el];
    eC = ei[num_edges + el];
  }

  // issue all 8 gathers back-to-back (2 per edge, 64B each)
  uint2 ar[4], ac[4];
#pragma unroll
  for (int s = 0; s < 4; ++s) {
    int nr = __shfl(eR, s * 8 + g, 64);
    int nc = __shfl(eC, s * 8 + g, 64);
    ar[s] = *(const uint2*)(P8 + (size_t)nr * 128 + h * 8);
    ac[s] = *(const uint2*)(P8 + (size_t)nc * 128 + 64 + h * 8);
  }

#pragma unroll
  for (int s = 0; s < 4; ++s) {
    float accv = 0.f;
#pragma unroll
    for (int j = 0; j < 4; ++j) {
      float hv = fmaxf(i8tof(ar[s].x, j) * st + i8tof(ac[s].x, j) * sb, 0.f);
      accv = fmaf(hv, w0[j], accv);
    }
#pragma unroll
    for (int j = 0; j < 4; ++j) {
      float hv = fmaxf(i8tof(ar[s].y, j) * st + i8tof(ac[s].y, j) * sb, 0.f);
      accv = fmaf(hv, w1v[j], accv);
    }
    accv += __shfl_xor(accv, 1, 64);
    accv += __shfl_xor(accv, 2, 64);
    accv += __shfl_xor(accv, 4, 64);
    if (h == 0) {
      int e = wbase + s * 8 + g;
      if (e < num_edges) {
        float a1 = fminf(fmaxf(u1[e], GS_EPS), 1.0f);
        float a2 = fminf(fmaxf(u2[e], GS_EPS), 1.0f);
        float g1 = -__logf(-__logf(a1));
        float g2 = -__logf(-__logf(a2));
        float x = accv + bias2 + g1 - g2;  // TEMP = 1.0
        out[e] = 1.f / (1.f + __expf(-x));
      }
    }
  }
}

extern "C" void kernel_launch(void* const* d_in, const int* in_sizes, int n_in,
                              void* d_out, int out_size, void* d_ws, size_t ws_size,
                              hipStream_t stream) {
  const float* node_embed = (const float*)d_in[0];
  const int* ei = (const int*)d_in[1];
  const float* u1 = (const float*)d_in[2];
  const float* u2 = (const float*)d_in[3];
  const float* W1 = (const float*)d_in[4];
  const float* b1 = (const float*)d_in[5];
  const float* W2 = (const float*)d_in[6];
  const float* b2 = (const float*)d_in[7];
  float* out = (float*)d_out;

  const int num_edges = in_sizes[2];        // u1 length
  const int num_nodes = in_sizes[0] / 128;  // embed_dim = 128

  // workspace layout (256B-aligned chunks)
  char* w = (char*)d_ws;
  unsigned short* P = (unsigned short*)w;   w += ((size_t)num_nodes * 128 * 2 + 255) & ~(size_t)255;
  uint8_t* P8 = (uint8_t*)w;                w += ((size_t)num_nodes * 128 + 255) & ~(size_t)255;
  uint32* gmax = (uint32*)w;                w += 256;
  unsigned short* w1g = (unsigned short*)w;

  conv_w1cat_kernel<<<8, 256, 0, stream>>>(W1, w1g, gmax);
  const int pblocks = (num_nodes + 127) / 128;
  pcompute_kernel<<<pblocks, 512, 0, stream>>>(node_embed, w1g, b1, P, gmax, num_nodes);
  const int total16 = num_nodes * 8;  // threads of 16 values
  quant_kernel<<<(total16 + 255) / 256, 256, 0, stream>>>(P, gmax, P8, total16);
  const int eblocks = (num_edges + 127) / 128;
  edge_kernel<<<eblocks, 256, 0, stream>>>(P8, gmax, ei, u1, u2, W2, b2, out, num_edges);
}

// Round 8
// 124.927 us; speedup vs baseline: 1.4716x; 1.4716x over previous
//
#include <hip/hip_runtime.h>
#include <stdint.h>

typedef float  floatx4 __attribute__((ext_vector_type(4)));
typedef short  short8  __attribute__((ext_vector_type(8)));
typedef float  f4v     __attribute__((ext_vector_type(4)));
typedef unsigned int uint32;

#define GS_EPS 1e-10f

__device__ __forceinline__ unsigned short f2bf(float x) {
  uint32 u = __float_as_uint(x);
  u += 0x7FFFu + ((u >> 16) & 1u);
  return (unsigned short)(u >> 16);
}
__device__ __forceinline__ float bf2f(short v) {
  return __uint_as_float(((uint32)(unsigned short)v) << 16);
}
// sign-extend byte j (0..3) of w, to float
__device__ __forceinline__ float i8tof(uint32 w, int j) {
  int b = (int)(w << (24 - 8 * j)) >> 24;
  return (float)b;
}

// ---- prep: W1 fp32 [256][64] -> W1cat bf16 blocked [chunk=k/8][n=0..128)][k%8]
// W1cat[k][n] = n<64 ? W1[k][n] : W1[128+k][n-64]; also zero the gmax slots.
__global__ void conv_w1cat_kernel(const float* __restrict__ W1,
                                  unsigned short* __restrict__ w1g,
                                  uint32* __restrict__ gmax) {
  if (blockIdx.x == 0 && threadIdx.x < 2) gmax[threadIdx.x] = 0u;
  int i = blockIdx.x * 256 + threadIdx.x;  // 0..2047 = chunk*128 + n
  int chunk = i >> 7;
  int n = i & 127;
  const float* src = (n < 64) ? (W1 + n) : (W1 + 128 * 64 + (n - 64));
  uint32 d[4];
#pragma unroll
  for (int j = 0; j < 4; ++j) {
    int k0 = chunk * 8 + 2 * j;
    unsigned short lo = f2bf(src[(size_t)k0 * 64]);
    unsigned short hi = f2bf(src[(size_t)(k0 + 1) * 64]);
    d[j] = (uint32)lo | ((uint32)hi << 16);
  }
#pragma unroll
  for (int j = 0; j < 4; ++j) *(uint32*)&w1g[(size_t)i * 8 + 2 * j] = d[j];
}

// ---- precompute P[node][0:64]=e@W1_top+b1, P[node][64:128]=e@W1_bot (bf16),
// plus global absmax of each half. Atomic fan-in: wave-shfl reduce -> LDS
// block reduce -> ONE thread per block does the 2 atomicMax (782 total,
// vs R7's 6256 contended RMWs that serialized at ~25 cyc each = +65 µs). ----
__global__ __launch_bounds__(512, 4) void pcompute_kernel(
    const float* __restrict__ E, const unsigned short* __restrict__ w1g,
    const float* __restrict__ b1, unsigned short* __restrict__ P,
    uint32* __restrict__ gmax, int num_nodes) {
  __shared__ __align__(16) unsigned short w1blk[16 * 128 * 8];  // 32 KB
  __shared__ float wmt[8], wmb[8];

  const int tid = threadIdx.x;
  const int wave = tid >> 6;
  const int lane = tid & 63;
  const int q = lane >> 4;
  const int l16 = lane & 15;

#pragma unroll
  for (int it = 0; it < 4; ++it) {
    int idx = it * 512 + tid;
    short8 v = *(const short8*)(w1g + (size_t)idx * 8);
    *(short8*)&w1blk[(size_t)idx * 8] = v;
  }

  const int rowbase = blockIdx.x * 128 + wave * 16;
  int row = rowbase + l16;
  const bool ok = row < num_nodes;
  if (!ok) row = num_nodes - 1;

  short8 bfr[4];
#pragma unroll
  for (int kk = 0; kk < 4; ++kk) {
    const float* p = E + (size_t)row * 128 + kk * 32 + q * 8;
    f4v v0 = *(const f4v*)p;
    f4v v1 = *(const f4v*)(p + 4);
    short8 t;
    t[0] = (short)f2bf(v0[0]); t[1] = (short)f2bf(v0[1]);
    t[2] = (short)f2bf(v0[2]); t[3] = (short)f2bf(v0[3]);
    t[4] = (short)f2bf(v1[0]); t[5] = (short)f2bf(v1[1]);
    t[6] = (short)f2bf(v1[2]); t[7] = (short)f2bf(v1[3]);
    bfr[kk] = t;
  }
  __syncthreads();

  floatx4 acc[8];
#pragma unroll
  for (int t = 0; t < 8; ++t) {
    floatx4 z = {0.f, 0.f, 0.f, 0.f};
    acc[t] = z;
  }
#pragma unroll
  for (int kk = 0; kk < 4; ++kk) {
#pragma unroll
    for (int t = 0; t < 8; ++t) {
      short8 af = *(const short8*)&w1blk[(size_t)((kk * 4 + q) * 128 + t * 16 + l16) * 8];
      acc[t] = __builtin_amdgcn_mfma_f32_16x16x32_bf16(af, bfr[kk], acc[t], 0, 0, 0);
    }
  }

  // fold b1 into top half (j<64 <=> t<4); write bf16 P; track half absmax
  float mtop = 0.f, mbot = 0.f;
#pragma unroll
  for (int t = 0; t < 8; ++t) {
    floatx4 a = acc[t];
    if (t < 4) {
      f4v bv = *(const f4v*)(b1 + t * 16 + q * 4);
      a[0] += bv[0]; a[1] += bv[1]; a[2] += bv[2]; a[3] += bv[3];
    }
    float m = fmaxf(fmaxf(fabsf(a[0]), fabsf(a[1])), fmaxf(fabsf(a[2]), fabsf(a[3])));
    if (t < 4) mtop = fmaxf(mtop, m); else mbot = fmaxf(mbot, m);
    uint32 lo = (uint32)f2bf(a[0]) | ((uint32)f2bf(a[1]) << 16);
    uint32 hi = (uint32)f2bf(a[2]) | ((uint32)f2bf(a[3]) << 16);
    if (ok) {
      uint32* dst = (uint32*)(P + (size_t)(rowbase + l16) * 128 + t * 16 + q * 4);
      dst[0] = lo;
      dst[1] = hi;
    }
  }
  // wave reduce -> LDS -> block reduce -> one atomic pair per block
#pragma unroll
  for (int s = 1; s < 64; s <<= 1) {
    mtop = fmaxf(mtop, __shfl_xor(mtop, s, 64));
    mbot = fmaxf(mbot, __shfl_xor(mbot, s, 64));
  }
  if (lane == 0) {
    wmt[wave] = mtop;
    wmb[wave] = mbot;
  }
  __syncthreads();
  if (tid == 0) {
    float a = wmt[0], b = wmb[0];
#pragma unroll
    for (int i = 1; i < 8; ++i) {
      a = fmaxf(a, wmt[i]);
      b = fmaxf(b, wmb[i]);
    }
    atomicMax(&gmax[0], __float_as_uint(a));  // positive floats: uint order ok
    atomicMax(&gmax[1], __float_as_uint(b));
  }
}

// ---- quantize bf16 P -> combined int8 table P8[node][128] = {top64, bot64} ----
__global__ __launch_bounds__(256) void quant_kernel(
    const unsigned short* __restrict__ P, const uint32* __restrict__ gmax,
    uint8_t* __restrict__ P8, int total16) {
  int i = blockIdx.x * 256 + threadIdx.x;  // one thread = 16 values
  if (i >= total16) return;
  const float at = __uint_as_float(gmax[0]);
  const float ab = __uint_as_float(gmax[1]);
  const float invt = 127.f / fmaxf(at, 1e-20f);
  const float invb = 127.f / fmaxf(ab, 1e-20f);
  // offset i*16; within a 128-elem row, (i&7)<4 -> top half
  const float inv = ((i & 7) < 4) ? invt : invb;
  const size_t off = (size_t)i * 16;
  short8 v0 = *(const short8*)(P + off);
  short8 v1 = *(const short8*)(P + off + 8);
  uint32 outw[4];
#pragma unroll
  for (int w = 0; w < 4; ++w) {
    uint32 r = 0;
#pragma unroll
    for (int j = 0; j < 4; ++j) {
      short s = (w < 2) ? v0[w * 4 + j] : v1[(w - 2) * 4 + j];
      float x = bf2f(s) * inv;
      x = fminf(fmaxf(x, -127.f), 127.f);
      int vq = (int)__builtin_rintf(x);
      r |= ((uint32)(vq & 255)) << (8 * j);
    }
    outw[w] = r;
  }
  *(uint4*)(P8 + off) = *(uint4*)outw;
}

// ---- edge kernel: 2 random 64B gathers/edge + dequant dot + gumbel-sigmoid ----
// Block 256 = 4 waves; wave = 32 edges = 4 slots of 8 edges; 8 lanes/edge.
// (unchanged from R7 — measured ~20-21 µs there)
__global__ __launch_bounds__(256, 8) void edge_kernel(
    const uint8_t* __restrict__ P8, const uint32* __restrict__ gmax,
    const int* __restrict__ ei,
    const float* __restrict__ u1, const float* __restrict__ u2,
    const float* __restrict__ W2, const float* __restrict__ b2,
    float* __restrict__ out, int num_edges) {
  const int tid = threadIdx.x;
  const int wave = tid >> 6;
  const int lane = tid & 63;
  const int g = lane >> 3;  // edge-within-slot
  const int h = lane & 7;   // lane-within-edge
  const int wbase = blockIdx.x * 128 + wave * 32;

  const float st = __uint_as_float(gmax[0]) * (1.f / 127.f);  // uniform scalar
  const float sb = __uint_as_float(gmax[1]) * (1.f / 127.f);
  f4v w0 = *(const f4v*)(W2 + h * 8);
  f4v w1v = *(const f4v*)(W2 + h * 8 + 4);
  const float bias2 = b2[0];

  int el = wbase + (lane & 31);
  if (el > num_edges - 1) el = num_edges - 1;
  // int64-vs-int32 detection (per-wave uniform): int64 LE => odd words all 0
  unsigned long long oddmask = __ballot(ei[2 * el + 1] != 0);
  const bool idx64 = (oddmask == 0ULL);
  int eR, eC;
  if (idx64) {
    eR = ei[2 * el];
    eC = ei[2 * (num_edges + el)];
  } else {
    eR = ei[el];
    eC = ei[num_edges + el];
  }

  // issue all 8 gathers back-to-back (2 per edge, 64B each)
  uint2 ar[4], ac[4];
#pragma unroll
  for (int s = 0; s < 4; ++s) {
    int nr = __shfl(eR, s * 8 + g, 64);
    int nc = __shfl(eC, s * 8 + g, 64);
    ar[s] = *(const uint2*)(P8 + (size_t)nr * 128 + h * 8);
    ac[s] = *(const uint2*)(P8 + (size_t)nc * 128 + 64 + h * 8);
  }

#pragma unroll
  for (int s = 0; s < 4; ++s) {
    float accv = 0.f;
#pragma unroll
    for (int j = 0; j < 4; ++j) {
      float hv = fmaxf(i8tof(ar[s].x, j) * st + i8tof(ac[s].x, j) * sb, 0.f);
      accv = fmaf(hv, w0[j], accv);
    }
#pragma unroll
    for (int j = 0; j < 4; ++j) {
      float hv = fmaxf(i8tof(ar[s].y, j) * st + i8tof(ac[s].y, j) * sb, 0.f);
      accv = fmaf(hv, w1v[j], accv);
    }
    accv += __shfl_xor(accv, 1, 64);
    accv += __shfl_xor(accv, 2, 64);
    accv += __shfl_xor(accv, 4, 64);
    if (h == 0) {
      int e = wbase + s * 8 + g;
      if (e < num_edges) {
        float a1 = fminf(fmaxf(u1[e], GS_EPS), 1.0f);
        float a2 = fminf(fmaxf(u2[e], GS_EPS), 1.0f);
        float g1 = -__logf(-__logf(a1));
        float g2 = -__logf(-__logf(a2));
        float x = accv + bias2 + g1 - g2;  // TEMP = 1.0
        out[e] = 1.f / (1.f + __expf(-x));
      }
    }
  }
}

extern "C" void kernel_launch(void* const* d_in, const int* in_sizes, int n_in,
                              void* d_out, int out_size, void* d_ws, size_t ws_size,
                              hipStream_t stream) {
  const float* node_embed = (const float*)d_in[0];
  const int* ei = (const int*)d_in[1];
  const float* u1 = (const float*)d_in[2];
  const float* u2 = (const float*)d_in[3];
  const float* W1 = (const float*)d_in[4];
  const float* b1 = (const float*)d_in[5];
  const float* W2 = (const float*)d_in[6];
  const float* b2 = (const float*)d_in[7];
  float* out = (float*)d_out;

  const int num_edges = in_sizes[2];        // u1 length
  const int num_nodes = in_sizes[0] / 128;  // embed_dim = 128

  // workspace layout (256B-aligned chunks)
  char* w = (char*)d_ws;
  unsigned short* P = (unsigned short*)w;   w += ((size_t)num_nodes * 128 * 2 + 255) & ~(size_t)255;
  uint8_t* P8 = (uint8_t*)w;                w += ((size_t)num_nodes * 128 + 255) & ~(size_t)255;
  uint32* gmax = (uint32*)w;                w += 256;
  unsigned short* w1g = (unsigned short*)w;

  conv_w1cat_kernel<<<8, 256, 0, stream>>>(W1, w1g, gmax);
  const int pblocks = (num_nodes + 127) / 128;
  pcompute_kernel<<<pblocks, 512, 0, stream>>>(node_embed, w1g, b1, P, gmax, num_nodes);
  const int total16 = num_nodes * 8;  // threads of 16 values
  quant_kernel<<<(total16 + 255) / 256, 256, 0, stream>>>(P, gmax, P8, total16);
  const int eblocks = (num_edges + 127) / 128;
  edge_kernel<<<eblocks, 256, 0, stream>>>(P8, gmax, ei, u1, u2, W2, b2, out, num_edges);
}

// Round 9
// 115.878 us; speedup vs baseline: 1.5865x; 1.0781x over previous
//
#include <hip/hip_runtime.h>
#include <stdint.h>

typedef float  floatx4 __attribute__((ext_vector_type(4)));
typedef short  short8  __attribute__((ext_vector_type(8)));
typedef float  f4v     __attribute__((ext_vector_type(4)));
typedef unsigned int uint32;

#define GS_EPS 1e-10f

__device__ __forceinline__ unsigned short f2bf(float x) {
  uint32 u = __float_as_uint(x);
  u += 0x7FFFu + ((u >> 16) & 1u);
  return (unsigned short)(u >> 16);
}
// sign-extend byte j (0..3) of w, to float
__device__ __forceinline__ float i8tof(uint32 w, int j) {
  int b = (int)(w << (24 - 8 * j)) >> 24;
  return (float)b;
}
__device__ __forceinline__ uint32 pack4_i8(floatx4 a, float inv) {
  uint32 r = 0;
#pragma unroll
  for (int i = 0; i < 4; ++i) {
    float x = a[i] * inv;
    x = fminf(fmaxf(x, -127.f), 127.f);
    int v = (int)__builtin_rintf(x);
    r |= ((uint32)(v & 255)) << (8 * i);
  }
  return r;
}

// ---- prep: W1 fp32 [256][64] -> W1cat bf16 blocked [chunk=k/8][n=0..128)][k%8]
// W1cat[k][n] = n<64 ? W1[k][n] : W1[128+k][n-64]   (k in [0,128))
__global__ void conv_w1cat_kernel(const float* __restrict__ W1,
                                  unsigned short* __restrict__ w1g) {
  int i = blockIdx.x * 256 + threadIdx.x;  // 0..2047 = chunk*128 + n
  int chunk = i >> 7;
  int n = i & 127;
  const float* src = (n < 64) ? (W1 + n) : (W1 + 128 * 64 + (n - 64));
  uint32 d[4];
#pragma unroll
  for (int j = 0; j < 4; ++j) {
    int k0 = chunk * 8 + 2 * j;
    unsigned short lo = f2bf(src[(size_t)k0 * 64]);
    unsigned short hi = f2bf(src[(size_t)(k0 + 1) * 64]);
    d[j] = (uint32)lo | ((uint32)hi << 16);
  }
#pragma unroll
  for (int j = 0; j < 4; ++j) *(uint32*)&w1g[(size_t)i * 8 + 2 * j] = d[j];
}

// ---- precompute P8[node][128] = int8{ e@W1_top+b1 (64B) ; e@W1_bot (64B) },
// quantized with PER-BLOCK (128 nodes) top/bot scales -> Sc[block] (float2).
// No global atomics (R7 lesson), no bf16 intermediate / quant pass (R8 lesson).
// MFMA mapping (validated R4): D col = node = l16, row = j = t*16 + q*4 + r.
__global__ __launch_bounds__(512, 4) void pcompute_kernel(
    const float* __restrict__ E, const unsigned short* __restrict__ w1g,
    const float* __restrict__ b1, uint8_t* __restrict__ P8,
    float2* __restrict__ Sc, int num_nodes) {
  __shared__ __align__(16) unsigned short w1blk[16 * 128 * 8];  // 32 KB
  __shared__ float wmt[8], wmb[8];

  const int tid = threadIdx.x;
  const int wave = tid >> 6;
  const int lane = tid & 63;
  const int q = lane >> 4;
  const int l16 = lane & 15;

#pragma unroll
  for (int it = 0; it < 4; ++it) {
    int idx = it * 512 + tid;
    short8 v = *(const short8*)(w1g + (size_t)idx * 8);
    *(short8*)&w1blk[(size_t)idx * 8] = v;
  }

  const int rowbase = blockIdx.x * 128 + wave * 16;
  int row = rowbase + l16;
  const bool ok = row < num_nodes;
  if (!ok) row = num_nodes - 1;

  short8 bfr[4];
#pragma unroll
  for (int kk = 0; kk < 4; ++kk) {
    const float* p = E + (size_t)row * 128 + kk * 32 + q * 8;
    f4v v0 = *(const f4v*)p;
    f4v v1 = *(const f4v*)(p + 4);
    short8 t;
    t[0] = (short)f2bf(v0[0]); t[1] = (short)f2bf(v0[1]);
    t[2] = (short)f2bf(v0[2]); t[3] = (short)f2bf(v0[3]);
    t[4] = (short)f2bf(v1[0]); t[5] = (short)f2bf(v1[1]);
    t[6] = (short)f2bf(v1[2]); t[7] = (short)f2bf(v1[3]);
    bfr[kk] = t;
  }
  __syncthreads();

  floatx4 acc[8];
#pragma unroll
  for (int t = 0; t < 8; ++t) {
    floatx4 z = {0.f, 0.f, 0.f, 0.f};
    acc[t] = z;
  }
#pragma unroll
  for (int kk = 0; kk < 4; ++kk) {
#pragma unroll
    for (int t = 0; t < 8; ++t) {
      short8 af = *(const short8*)&w1blk[(size_t)((kk * 4 + q) * 128 + t * 16 + l16) * 8];
      acc[t] = __builtin_amdgcn_mfma_f32_16x16x32_bf16(af, bfr[kk], acc[t], 0, 0, 0);
    }
  }

  // fold b1 into top half (j<64 <=> t<4); per-lane half absmax
  float mtop = 0.f, mbot = 0.f;
#pragma unroll
  for (int t = 0; t < 8; ++t) {
    floatx4 a = acc[t];
    if (t < 4) {
      f4v bv = *(const f4v*)(b1 + t * 16 + q * 4);
      a[0] += bv[0]; a[1] += bv[1]; a[2] += bv[2]; a[3] += bv[3];
      acc[t] = a;
    }
    float m = fmaxf(fmaxf(fabsf(a[0]), fabsf(a[1])), fmaxf(fabsf(a[2]), fabsf(a[3])));
    if (t < 4) mtop = fmaxf(mtop, m); else mbot = fmaxf(mbot, m);
  }
  // wave reduce -> LDS -> block reduce (all threads read 8 floats; no atomics)
#pragma unroll
  for (int s = 1; s < 64; s <<= 1) {
    mtop = fmaxf(mtop, __shfl_xor(mtop, s, 64));
    mbot = fmaxf(mbot, __shfl_xor(mbot, s, 64));
  }
  if (lane == 0) {
    wmt[wave] = mtop;
    wmb[wave] = mbot;
  }
  __syncthreads();
  float bt = wmt[0], bb = wmb[0];
#pragma unroll
  for (int i = 1; i < 8; ++i) {
    bt = fmaxf(bt, wmt[i]);
    bb = fmaxf(bb, wmb[i]);
  }
  const float invt = 127.f / fmaxf(bt, 1e-20f);
  const float invb = 127.f / fmaxf(bb, 1e-20f);

  if (ok) {
    const int node = rowbase + l16;
#pragma unroll
    for (int t = 0; t < 8; ++t) {
      *(uint32*)(P8 + (size_t)node * 128 + t * 16 + q * 4) =
          pack4_i8(acc[t], (t < 4) ? invt : invb);
    }
  }
  if (tid == 0)
    Sc[blockIdx.x] = make_float2(bt * (1.f / 127.f), bb * (1.f / 127.f));
}

// ---- edge kernel: 2 random 64B gathers/edge + dequant dot + gumbel-sigmoid ----
// Block 256 = 4 waves; wave = 32 edges = 4 slots of 8 edges; 8 lanes/edge.
// Scales come from the ~3 KB per-block table (node>>7) — L1-resident.
__global__ __launch_bounds__(256, 8) void edge_kernel(
    const uint8_t* __restrict__ P8, const float2* __restrict__ Sc,
    const int* __restrict__ ei,
    const float* __restrict__ u1, const float* __restrict__ u2,
    const float* __restrict__ W2, const float* __restrict__ b2,
    float* __restrict__ out, int num_edges) {
  const int tid = threadIdx.x;
  const int wave = tid >> 6;
  const int lane = tid & 63;
  const int g = lane >> 3;  // edge-within-slot
  const int h = lane & 7;   // lane-within-edge
  const int wbase = blockIdx.x * 128 + wave * 32;

  f4v w0 = *(const f4v*)(W2 + h * 8);
  f4v w1v = *(const f4v*)(W2 + h * 8 + 4);
  const float bias2 = b2[0];

  int el = wbase + (lane & 31);
  if (el > num_edges - 1) el = num_edges - 1;
  // int64-vs-int32 detection (per-wave uniform): int64 LE => odd words all 0
  unsigned long long oddmask = __ballot(ei[2 * el + 1] != 0);
  const bool idx64 = (oddmask == 0ULL);
  int eR, eC;
  if (idx64) {
    eR = ei[2 * el];
    eC = ei[2 * (num_edges + el)];
  } else {
    eR = ei[el];
    eC = ei[num_edges + el];
  }

  // issue all 8 data gathers back-to-back (2 per edge, 64B each) + tiny scale reads
  uint2 ar[4], ac[4];
  float srv[4], scv[4];
#pragma unroll
  for (int s = 0; s < 4; ++s) {
    int nr = __shfl(eR, s * 8 + g, 64);
    int nc = __shfl(eC, s * 8 + g, 64);
    ar[s] = *(const uint2*)(P8 + (size_t)nr * 128 + h * 8);
    ac[s] = *(const uint2*)(P8 + (size_t)nc * 128 + 64 + h * 8);
    srv[s] = Sc[nr >> 7].x;  // top-half scale of row node's block
    scv[s] = Sc[nc >> 7].y;  // bot-half scale of col node's block
  }

#pragma unroll
  for (int s = 0; s < 4; ++s) {
    float accv = 0.f;
    const float st = srv[s], sb = scv[s];
#pragma unroll
    for (int j = 0; j < 4; ++j) {
      float hv = fmaxf(i8tof(ar[s].x, j) * st + i8tof(ac[s].x, j) * sb, 0.f);
      accv = fmaf(hv, w0[j], accv);
    }
#pragma unroll
    for (int j = 0; j < 4; ++j) {
      float hv = fmaxf(i8tof(ar[s].y, j) * st + i8tof(ac[s].y, j) * sb, 0.f);
      accv = fmaf(hv, w1v[j], accv);
    }
    accv += __shfl_xor(accv, 1, 64);
    accv += __shfl_xor(accv, 2, 64);
    accv += __shfl_xor(accv, 4, 64);
    if (h == 0) {
      int e = wbase + s * 8 + g;
      if (e < num_edges) {
        float a1 = fminf(fmaxf(u1[e], GS_EPS), 1.0f);
        float a2 = fminf(fmaxf(u2[e], GS_EPS), 1.0f);
        float g1 = -__logf(-__logf(a1));
        float g2 = -__logf(-__logf(a2));
        float x = accv + bias2 + g1 - g2;  // TEMP = 1.0
        out[e] = 1.f / (1.f + __expf(-x));
      }
    }
  }
}

extern "C" void kernel_launch(void* const* d_in, const int* in_sizes, int n_in,
                              void* d_out, int out_size, void* d_ws, size_t ws_size,
                              hipStream_t stream) {
  const float* node_embed = (const float*)d_in[0];
  const int* ei = (const int*)d_in[1];
  const float* u1 = (const float*)d_in[2];
  const float* u2 = (const float*)d_in[3];
  const float* W1 = (const float*)d_in[4];
  const float* b1 = (const float*)d_in[5];
  const float* W2 = (const float*)d_in[6];
  const float* b2 = (const float*)d_in[7];
  float* out = (float*)d_out;

  const int num_edges = in_sizes[2];        // u1 length
  const int num_nodes = in_sizes[0] / 128;  // embed_dim = 128
  const int pblocks = (num_nodes + 127) / 128;

  // workspace layout (256B-aligned chunks)
  char* w = (char*)d_ws;
  uint8_t* P8 = (uint8_t*)w;   w += ((size_t)num_nodes * 128 + 255) & ~(size_t)255;
  float2* Sc = (float2*)w;     w += ((size_t)pblocks * sizeof(float2) + 255) & ~(size_t)255;
  unsigned short* w1g = (unsigned short*)w;

  conv_w1cat_kernel<<<8, 256, 0, stream>>>(W1, w1g);
  pcompute_kernel<<<pblocks, 512, 0, stream>>>(node_embed, w1g, b1, P8, Sc, num_nodes);
  const int eblocks = (num_edges + 127) / 128;
  edge_kernel<<<eblocks, 256, 0, stream>>>(P8, Sc, ei, u1, u2, W2, b2, out, num_edges);
}